// Round 1
// baseline (204.736 us; speedup 1.0000x reference)
//
#include <hip/hip_runtime.h>

// Tall-skinny GEMM: out[65536,64] = x[65536,512] @ W[512,64], all fp32 in/out.
// Strategy: bf16 MFMA (16x16x32) -> compute is ~1.7us at 2.5PF, kernel is a
// pure 151MB stream (~24us floor at 6.3TB/s). W is converted once per launch
// into MFMA B-fragment layout in d_ws, staged to LDS per block.

#define BATCH 65536
#define KDIM  512
#define NDIM  64

typedef __attribute__((ext_vector_type(8))) short short8;   // 8 bf16 = 4 VGPRs
typedef __attribute__((ext_vector_type(4))) float f32x4;    // MFMA accumulator

__device__ __forceinline__ unsigned short f2bf(float f) {
    // round-to-nearest-even fp32 -> bf16
    unsigned int u = __float_as_uint(f);
    u += 0x7FFFu + ((u >> 16) & 1u);
    return (unsigned short)(u >> 16);
}

// ---------------------------------------------------------------------------
// Prep: W[512,64] fp32 -> bf16 B-fragments in d_ws.
// Slot s = (kt*4 + nt)*64 + lane holds 8 bf16: B[kt*32 + 8*(lane>>4) + j][nt*16 + (lane&15)]
// 4096 slots * 16B = 64KB.
// ---------------------------------------------------------------------------
__global__ void prep_w(const float* __restrict__ W, uint4* __restrict__ ws) {
    int t = blockIdx.x * 256 + threadIdx.x;   // 0..4095
    int l = t & 63;
    int ntkt = t >> 6;
    int nt = ntkt & 3, kt = ntkt >> 2;
    int n = nt * 16 + (l & 15);
    int kbase = kt * 32 + (l >> 4) * 8;
    unsigned int p[4];
#pragma unroll
    for (int jj = 0; jj < 4; ++jj) {
        unsigned int lo = f2bf(W[(kbase + 2 * jj    ) * NDIM + n]);
        unsigned int hi = f2bf(W[(kbase + 2 * jj + 1) * NDIM + n]);
        p[jj] = lo | (hi << 16);
    }
    uint4 v; v.x = p[0]; v.y = p[1]; v.z = p[2]; v.w = p[3];
    ws[t] = v;
}

// ---------------------------------------------------------------------------
// Main: each block = 256 thr = 4 waves; block handles 64 rows, wave 16 rows.
// grid = 65536/64 = 1024 blocks.
// ---------------------------------------------------------------------------
__global__ __launch_bounds__(256, 2) void gemm_tall(
    const float* __restrict__ x, const float* __restrict__ W,
    const uint4* __restrict__ wsB, float* __restrict__ out, int prepped)
{
    __shared__ __align__(16) unsigned short Bl[32768];   // 64KB bf16 B-fragments

    const int tid = threadIdx.x;

    if (prepped) {
        uint4* dst = (uint4*)Bl;
        for (int i = tid; i < 4096; i += 256) dst[i] = wsB[i];
    } else {
        // fallback: gather straight from fp32 W (same layout as prep_w)
        for (int s = tid; s < 4096; s += 256) {
            int l = s & 63;
            int ntkt = s >> 6;
            int nt = ntkt & 3, kt = ntkt >> 2;
            int n = nt * 16 + (l & 15);
            int kbase = kt * 32 + (l >> 4) * 8;
            unsigned short* d = &Bl[s * 8];
#pragma unroll
            for (int j = 0; j < 8; ++j) d[j] = f2bf(W[(kbase + j) * NDIM + n]);
        }
    }
    __syncthreads();

    const int wave = tid >> 6;
    const int lane = tid & 63;
    const int c = lane & 15;          // A row within stripe / C col
    const int q = lane >> 4;          // k-quad
    const int rowBase = blockIdx.x * 64 + wave * 16;
    const float* xr = x + (size_t)(rowBase + c) * KDIM + q * 8;
    const short8* Bf = (const short8*)Bl;

    f32x4 acc[4] = {{0.f,0.f,0.f,0.f},{0.f,0.f,0.f,0.f},
                    {0.f,0.f,0.f,0.f},{0.f,0.f,0.f,0.f}};

    // software-pipelined A load: k = kt*32 + q*8 + j, j in [0,8)
    float4 a0 = *(const float4*)(xr);
    float4 a1 = *(const float4*)(xr + 4);
#pragma unroll
    for (int kt = 0; kt < 16; ++kt) {
        float4 p0 = a0, p1 = a1;
        if (kt < 15) {
            a0 = *(const float4*)(xr + (kt + 1) * 32);
            a1 = *(const float4*)(xr + (kt + 1) * 32 + 4);
        }
        short8 af;
        af[0] = (short)f2bf(p0.x); af[1] = (short)f2bf(p0.y);
        af[2] = (short)f2bf(p0.z); af[3] = (short)f2bf(p0.w);
        af[4] = (short)f2bf(p1.x); af[5] = (short)f2bf(p1.y);
        af[6] = (short)f2bf(p1.z); af[7] = (short)f2bf(p1.w);
#pragma unroll
        for (int nt = 0; nt < 4; ++nt) {
            short8 bf = Bf[(kt * 4 + nt) * 64 + lane];
            acc[nt] = __builtin_amdgcn_mfma_f32_16x16x32_bf16(af, bf, acc[nt], 0, 0, 0);
        }
    }

    // C/D layout: col = lane&15, row = 4*(lane>>4) + i   [m89/m91 verified]
#pragma unroll
    for (int nt = 0; nt < 4; ++nt) {
#pragma unroll
        for (int i = 0; i < 4; ++i) {
            out[(size_t)(rowBase + q * 4 + i) * NDIM + nt * 16 + c] = acc[nt][i];
        }
    }
}

extern "C" void kernel_launch(void* const* d_in, const int* in_sizes, int n_in,
                              void* d_out, int out_size, void* d_ws, size_t ws_size,
                              hipStream_t stream) {
    const float* x = (const float*)d_in[0];
    const float* W = (const float*)d_in[1];
    float* out = (float*)d_out;

    if (ws_size >= 65536) {
        prep_w<<<16, 256, 0, stream>>>(W, (uint4*)d_ws);
        gemm_tall<<<1024, 256, 0, stream>>>(x, W, (const uint4*)d_ws, out, 1);
    } else {
        gemm_tall<<<1024, 256, 0, stream>>>(x, W, nullptr, out, 0);
    }
}